// Round 17
// baseline (292.987 us; speedup 1.0000x reference)
//
#include <hip/hip_runtime.h>
#include <hip/hip_bf16.h>

typedef __attribute__((ext_vector_type(8))) short short8;
typedef __attribute__((ext_vector_type(4))) float f32x4;

#define BB 8
#define NN 32768
#define KK 128
#define DD 64
#define TAU 1.0f
#define ITERS 10
#define EPSV 1e-8f
#define JPARTS 128
#define LOG2E 1.4426950408889634f

// ---- d_out layout (floats) ----
#define G_SZ   ((size_t)BB * NN * KK)
#define PI_OFF (G_SZ)
#define XY_OFF (PI_OFF + (size_t)BB * KK)
#define NF_OUT (XY_OFF + (size_t)BB * KK * 3)

// ---- d_ws layout (floats) ----
#define SLICE_F (BB * KK * 4)                  // 4096
#define HDR_F   ((ITERS + 1) * SLICE_F)        // acc slices 0..10 (slice 0 unused)

__device__ __forceinline__ unsigned pk2(float a, float b) {
    __hip_bfloat162 h = __float22bfloat162_rn(make_float2(a, b));
    unsigned u; __builtin_memcpy(&u, &h, 4); return u;
}
// raw v_exp_f32 (2^x), no OCML fixup, no log2e multiply
__device__ __forceinline__ float ex2(float x) { return __builtin_amdgcn_exp2f(x); }
// raw v_rcp_f32, 1-ulp
__device__ __forceinline__ float rcp(float x) { return __builtin_amdgcn_rcpf(x); }

// ============ assign: two-pass softmax, 256 pts/block, 4 blocks/CU ==============
// grid (128, B), block 256 (4 waves). Occupancy experiment: double resident
// waves (4/SIMD) to hide dep-chain latency now that VALU work is trimmed.
// pass1: 1 point/thread, 8 centers/iter -> 8 independent exp chains.
// pass2: lane owns clusters lane, lane+64; wave sweeps its 64 points.
template <bool FIRST, bool LAST>
__global__ __launch_bounds__(256) void assign_kernel(
    const float* __restrict__ xyz, const float* __restrict__ sc,
    const float4* __restrict__ accIn,   // slice it (unused if FIRST)
    float* __restrict__ accOut,         // slice it+1 (pre-zeroed)
    float* __restrict__ gamma_out)
{
    __shared__ float4 cLds[KK];      // {2cx,2cy,2cz,-|c|^2} * log2e/tau
    __shared__ float4 wLds[256];     // {x,y,z, s/l}
    __shared__ float  accW[4][512];

    const int b = blockIdx.y, blk = blockIdx.x;
    const int tid = threadIdx.x, wave = tid >> 6, lane = tid & 63;

    const float* X = xyz + (size_t)b * 3 * NN;
    const float* S = sc + (size_t)b * NN;

    const int n = blk * 256 + tid;
    const float px = X[n], py = X[NN + n], pz = X[2 * NN + n], ps = S[n];

    if (tid < KK) {
        float cx, cy, cz;
        if (FIRST) {
            int i0 = tid * (NN / KK);
            cx = X[i0]; cy = X[NN + i0]; cz = X[2 * NN + i0];
        } else {
            float4 a = accIn[b * KK + tid];
            float dn = rcp(a.w + EPSV);
            cx = a.x * dn; cy = a.y * dn; cz = a.z * dn;
        }
        const float s = LOG2E / TAU;
        cLds[tid] = make_float4(2.f * cx * s, 2.f * cy * s, 2.f * cz * s,
                                -(cx * cx + cy * cy + cz * cz) * s);
    }
    __syncthreads();

    // pass 1: own-point denominator, 8 centers/iter -> 8 independent exp chains
    float la = 0.f, lb = 0.f, lc = 0.f, ld = 0.f;
    float le = 0.f, lf = 0.f, lg = 0.f, lh = 0.f;
    #pragma unroll 4
    for (int k = 0; k < KK; k += 8) {
        float4 c0 = cLds[k],     c1 = cLds[k + 1];
        float4 c2 = cLds[k + 2], c3 = cLds[k + 3];
        float4 c4 = cLds[k + 4], c5 = cLds[k + 5];
        float4 c6 = cLds[k + 6], c7 = cLds[k + 7];
        la += ex2(fmaf(px, c0.x, fmaf(py, c0.y, fmaf(pz, c0.z, c0.w))));
        lb += ex2(fmaf(px, c1.x, fmaf(py, c1.y, fmaf(pz, c1.z, c1.w))));
        lc += ex2(fmaf(px, c2.x, fmaf(py, c2.y, fmaf(pz, c2.z, c2.w))));
        ld += ex2(fmaf(px, c3.x, fmaf(py, c3.y, fmaf(pz, c3.z, c3.w))));
        le += ex2(fmaf(px, c4.x, fmaf(py, c4.y, fmaf(pz, c4.z, c4.w))));
        lf += ex2(fmaf(px, c5.x, fmaf(py, c5.y, fmaf(pz, c5.z, c5.w))));
        lg += ex2(fmaf(px, c6.x, fmaf(py, c6.y, fmaf(pz, c6.z, c6.w))));
        lh += ex2(fmaf(px, c7.x, fmaf(py, c7.y, fmaf(pz, c7.z, c7.w))));
    }
    const float l = ((la + lb) + (lc + ld)) + ((le + lf) + (lg + lh));
    wLds[tid] = make_float4(px, py, pz, ps * rcp(l));
    __syncthreads();

    // pass 2: lane owns clusters lane, lane+64; wave sweeps its 64 points.
    const float4 c0 = cLds[lane];
    const float4 c1 = cLds[lane + 64];
    float ax0 = 0, ay0 = 0, az0 = 0, aw0 = 0;
    float ax1 = 0, ay1 = 0, az1 = 0, aw1 = 0;
    float* grow = gamma_out + ((size_t)b * NN + blk * 256 + (wave << 6)) * KK + lane;

    #pragma unroll 4
    for (int j = 0; j < 64; ++j) {
        float4 P = wLds[(wave << 6) | j];   // wave-uniform broadcast
        float g0 = ex2(fmaf(P.x, c0.x, fmaf(P.y, c0.y, fmaf(P.z, c0.z, c0.w)))) * P.w;
        float g1 = ex2(fmaf(P.x, c1.x, fmaf(P.y, c1.y, fmaf(P.z, c1.z, c1.w)))) * P.w;
        if (LAST) {
            grow[(size_t)j * KK] = g0;
            grow[(size_t)j * KK + 64] = g1;
        }
        ax0 = fmaf(g0, P.x, ax0); ay0 = fmaf(g0, P.y, ay0);
        az0 = fmaf(g0, P.z, az0); aw0 += g0;
        ax1 = fmaf(g1, P.x, ax1); ay1 = fmaf(g1, P.y, ay1);
        az1 = fmaf(g1, P.z, az1); aw1 += g1;
    }

    ((float4*)accW[wave])[lane]      = make_float4(ax0, ay0, az0, aw0);
    ((float4*)accW[wave])[lane + 64] = make_float4(ax1, ay1, az1, aw1);
    __syncthreads();
    float v0 = accW[0][tid]       + accW[1][tid]       + accW[2][tid]       + accW[3][tid];
    float v1 = accW[0][tid + 256] + accW[1][tid + 256] + accW[2][tid + 256] + accW[3][tid + 256];
    float* ag = accOut + b * (KK * 4);
    atomicAdd(ag + tid, v0);
    atomicAdd(ag + tid + 256, v1);
}

// ========= final: s_sum (inline) + node_xyz + pi from slice ITERS ==============
__global__ __launch_bounds__(256) void final_kernel(const float* __restrict__ sc,
                                                    const float* __restrict__ ws,
                                                    float* __restrict__ out) {
    int b = blockIdx.x, tid = threadIdx.x, wave = tid >> 6, lane = tid & 63;
    const float* S = sc + (size_t)b * NN;
    float sum = 0.f;
    for (int i = tid; i < NN; i += 256) sum += S[i];
    #pragma unroll
    for (int m = 1; m <= 32; m <<= 1) sum += __shfl_xor(sum, m, 64);
    __shared__ float red[4];
    if (lane == 0) red[wave] = sum;
    __syncthreads();
    if (tid < KK) {
        float ssum = red[0] + red[1] + red[2] + red[3] + EPSV;
        float4 a = ((const float4*)(ws + ITERS * SLICE_F))[b * KK + tid];
        float denom = a.w + EPSV;
        float* oxyz = out + XY_OFF + (size_t)(b * KK + tid) * 3;
        oxyz[0] = a.x / denom; oxyz[1] = a.y / denom; oxyz[2] = a.z / denom;
        out[PI_OFF + b * KK + tid] = a.w / ssum;
    }
}

// ====== nf_mfma2: nf[k][d] via 16x16x32 bf16 MFMA, atomic accumulate ======
__global__ __launch_bounds__(256) void nf_mfma2(const float* __restrict__ gamma,
                                                const float* __restrict__ feats,
                                                float* __restrict__ nf_acc) {
    __shared__ unsigned short gT[KK * 40];   // [k][pitch 40 bf16], 10240 B
    const int b = blockIdx.y, part = blockIdx.x;
    const int tid = threadIdx.x, wave = tid >> 6, lane = tid & 63;
    const int r = lane & 15, hi = lane >> 4;
    const int p = tid & 15, q0 = tid >> 4;

    f32x4 acc[2][4];
    #pragma unroll
    for (int kt = 0; kt < 2; kt++)
        #pragma unroll
        for (int dt = 0; dt < 4; dt++) acc[kt][dt] = (f32x4){0.f, 0.f, 0.f, 0.f};

    const float* gb = gamma + (size_t)b * NN * KK + (size_t)part * 256 * KK;
    const float* fb = feats + (size_t)b * DD * NN;
    const int n0 = part * 256;

    for (int ch = 0; ch < 8; ++ch) {
        const float* gr0 = gb + (size_t)(ch * 32 + 2 * p) * KK;
        const float* gr1 = gr0 + KK;
        unsigned* rowd = (unsigned*)gT;
        #pragma unroll
        for (int s = 0; s < 2; ++s) {
            int q = q0 + 16 * s;
            float4 x = *(const float4*)(gr0 + 4 * q);
            float4 y = *(const float4*)(gr1 + 4 * q);
            rowd[(4 * q + 0) * 20 + p] = pk2(x.x, y.x);
            rowd[(4 * q + 1) * 20 + p] = pk2(x.y, y.y);
            rowd[(4 * q + 2) * 20 + p] = pk2(x.z, y.z);
            rowd[(4 * q + 3) * 20 + p] = pk2(x.w, y.w);
        }
        __syncthreads();

        const unsigned short* a0p = gT + (wave * 32 + r) * 40 + hi * 8;
        short8 a0 = *(const short8*)a0p;
        short8 a1 = *(const short8*)(a0p + 16 * 40);
        const int nn = n0 + ch * 32 + hi * 8;
        #pragma unroll
        for (int dt = 0; dt < 4; ++dt) {
            const float* fr = fb + (size_t)(dt * 16 + r) * NN + nn;
            float4 x = *(const float4*)fr;
            float4 y = *(const float4*)(fr + 4);
            union { unsigned u[4]; short8 s; } bu;
            bu.u[0] = pk2(x.x, x.y); bu.u[1] = pk2(x.z, x.w);
            bu.u[2] = pk2(y.x, y.y); bu.u[3] = pk2(y.z, y.w);
            acc[0][dt] = __builtin_amdgcn_mfma_f32_16x16x32_bf16(a0, bu.s, acc[0][dt], 0, 0, 0);
            acc[1][dt] = __builtin_amdgcn_mfma_f32_16x16x32_bf16(a1, bu.s, acc[1][dt], 0, 0, 0);
        }
        __syncthreads();
    }

    float* nf = nf_acc + (size_t)b * KK * DD + (size_t)(wave * 32) * DD;
    #pragma unroll
    for (int kt = 0; kt < 2; kt++)
        #pragma unroll
        for (int dt = 0; dt < 4; dt++)
            #pragma unroll
            for (int rr = 0; rr < 4; rr++)
                atomicAdd(&nf[(kt * 16 + hi * 4 + rr) * DD + dt * 16 + r],
                          acc[kt][dt][rr]);
}

// ====== nf_finalize: divide accumulated nf by denom, in place ======
__global__ __launch_bounds__(256) void nf_finalize(const float* __restrict__ ws,
                                                   float* __restrict__ out) {
    int idx = blockIdx.x * 256 + threadIdx.x;   // [0, B*K*D)
    int bk = idx / DD;
    float denom = ws[ITERS * SLICE_F + bk * 4 + 3] + EPSV;
    out[NF_OUT + idx] = out[NF_OUT + idx] / denom;
}

extern "C" void kernel_launch(void* const* d_in, const int* in_sizes, int n_in,
                              void* d_out, int out_size, void* d_ws, size_t ws_size,
                              hipStream_t stream) {
    const float* xyz = (const float*)d_in[0];
    const float* feats = (const float*)d_in[1];
    const float* sc = (const float*)d_in[2];
    float* out = (float*)d_out;
    float* ws = (float*)d_ws;

    hipMemsetAsync(ws, 0, (size_t)HDR_F * sizeof(float), stream);
    hipMemsetAsync(out + NF_OUT, 0, (size_t)BB * KK * DD * sizeof(float), stream);

    assign_kernel<true, false><<<dim3(128, BB), 256, 0, stream>>>(
        xyz, sc, nullptr, ws + SLICE_F, out);
    for (int it = 1; it < ITERS - 1; it++) {
        assign_kernel<false, false><<<dim3(128, BB), 256, 0, stream>>>(
            xyz, sc, (const float4*)(ws + it * SLICE_F),
            ws + (it + 1) * SLICE_F, out);
    }
    assign_kernel<false, true><<<dim3(128, BB), 256, 0, stream>>>(
        xyz, sc, (const float4*)(ws + (ITERS - 1) * SLICE_F),
        ws + ITERS * SLICE_F, out);

    final_kernel<<<BB, 256, 0, stream>>>(sc, ws, out);
    nf_mfma2<<<dim3(JPARTS, BB), 256, 0, stream>>>(out, feats, out + NF_OUT);
    nf_finalize<<<256, 256, 0, stream>>>(ws, out);
}

// Round 18
// 281.103 us; speedup vs baseline: 1.0423x; 1.0423x over previous
//
#include <hip/hip_runtime.h>
#include <hip/hip_bf16.h>

typedef __attribute__((ext_vector_type(8))) short short8;
typedef __attribute__((ext_vector_type(4))) float f32x4;

#define BB 8
#define NN 32768
#define KK 128
#define DD 64
#define TAU 1.0f
#define ITERS 10
#define EPSV 1e-8f
#define JPARTS 128
#define LOG2E 1.4426950408889634f

// ---- d_out layout (floats) ----
#define G_SZ   ((size_t)BB * NN * KK)
#define PI_OFF (G_SZ)
#define XY_OFF (PI_OFF + (size_t)BB * KK)
#define NF_OUT (XY_OFF + (size_t)BB * KK * 3)

// ---- d_ws layout (floats) ----
#define SLICE_F (BB * KK * 4)                  // 4096
#define HDR_F   ((ITERS + 1) * SLICE_F)        // acc slices 0..10 (slice 0 unused)

__device__ __forceinline__ unsigned pk2(float a, float b) {
    __hip_bfloat162 h = __float22bfloat162_rn(make_float2(a, b));
    unsigned u; __builtin_memcpy(&u, &h, 4); return u;
}
// raw v_exp_f32 (2^x), no OCML fixup, no log2e multiply
__device__ __forceinline__ float ex2(float x) { return __builtin_amdgcn_exp2f(x); }
// raw v_rcp_f32, 1-ulp
__device__ __forceinline__ float rcp(float x) { return __builtin_amdgcn_rcpf(x); }

// ============ assign: two-pass softmax, log2e-folded centers, 8-chain pass1 =====
// grid (64, B), block 256 (4 waves), 512 points/block.  (R16 — session best)
// 512 pts/block @ 2 blocks/CU is the measured optimum (R7/R16 vs R17).
template <bool FIRST, bool LAST>
__global__ __launch_bounds__(256) void assign_kernel(
    const float* __restrict__ xyz, const float* __restrict__ sc,
    const float4* __restrict__ accIn,   // slice it (unused if FIRST)
    float* __restrict__ accOut,         // slice it+1 (pre-zeroed)
    float* __restrict__ gamma_out)
{
    __shared__ float4 cLds[KK];      // {2cx,2cy,2cz,-|c|^2} * log2e/tau
    __shared__ float4 wLds[512];     // {x,y,z, s/l}
    __shared__ float  accW[4][512];

    const int b = blockIdx.y, blk = blockIdx.x;
    const int tid = threadIdx.x, wave = tid >> 6, lane = tid & 63;

    const float* X = xyz + (size_t)b * 3 * NN;
    const float* S = sc + (size_t)b * NN;

    const int n = blk * 512 + tid;
    const float px0 = X[n],       py0 = X[NN + n],       pz0 = X[2 * NN + n],       ps0 = S[n];
    const float px1 = X[n + 256], py1 = X[NN + n + 256], pz1 = X[2 * NN + n + 256], ps1 = S[n + 256];

    if (tid < KK) {
        float cx, cy, cz;
        if (FIRST) {
            int i0 = tid * (NN / KK);
            cx = X[i0]; cy = X[NN + i0]; cz = X[2 * NN + i0];
        } else {
            float4 a = accIn[b * KK + tid];
            float dn = rcp(a.w + EPSV);
            cx = a.x * dn; cy = a.y * dn; cz = a.z * dn;
        }
        const float s = LOG2E / TAU;
        cLds[tid] = make_float4(2.f * cx * s, 2.f * cy * s, 2.f * cz * s,
                                -(cx * cx + cy * cy + cz * cz) * s);
    }
    __syncthreads();

    // pass 1: denominators for 2 points/thread over 4 centers/iter
    // -> 8 independent exp chains (trans-latency hiding).
    float l0a = 0.f, l0b = 0.f, l0c = 0.f, l0d = 0.f;
    float l1a = 0.f, l1b = 0.f, l1c = 0.f, l1d = 0.f;
    #pragma unroll 4
    for (int k = 0; k < KK; k += 4) {
        float4 ca = cLds[k],     cb = cLds[k + 1];
        float4 cc = cLds[k + 2], cd = cLds[k + 3];
        l0a += ex2(fmaf(px0, ca.x, fmaf(py0, ca.y, fmaf(pz0, ca.z, ca.w))));
        l1a += ex2(fmaf(px1, ca.x, fmaf(py1, ca.y, fmaf(pz1, ca.z, ca.w))));
        l0b += ex2(fmaf(px0, cb.x, fmaf(py0, cb.y, fmaf(pz0, cb.z, cb.w))));
        l1b += ex2(fmaf(px1, cb.x, fmaf(py1, cb.y, fmaf(pz1, cb.z, cb.w))));
        l0c += ex2(fmaf(px0, cc.x, fmaf(py0, cc.y, fmaf(pz0, cc.z, cc.w))));
        l1c += ex2(fmaf(px1, cc.x, fmaf(py1, cc.y, fmaf(pz1, cc.z, cc.w))));
        l0d += ex2(fmaf(px0, cd.x, fmaf(py0, cd.y, fmaf(pz0, cd.z, cd.w))));
        l1d += ex2(fmaf(px1, cd.x, fmaf(py1, cd.y, fmaf(pz1, cd.z, cd.w))));
    }
    const float l0 = (l0a + l0b) + (l0c + l0d);
    const float l1 = (l1a + l1b) + (l1c + l1d);
    wLds[tid]       = make_float4(px0, py0, pz0, ps0 * rcp(l0));
    wLds[tid + 256] = make_float4(px1, py1, pz1, ps1 * rcp(l1));
    __syncthreads();

    // pass 2: lane owns clusters lane, lane+64; wave sweeps its 128 points.
    const float4 c0 = cLds[lane];
    const float4 c1 = cLds[lane + 64];
    float ax0 = 0, ay0 = 0, az0 = 0, aw0 = 0;
    float ax1 = 0, ay1 = 0, az1 = 0, aw1 = 0;
    float* grow = gamma_out + ((size_t)b * NN + blk * 512 + (wave << 7)) * KK + lane;

    #pragma unroll 4
    for (int j = 0; j < 128; ++j) {
        float4 P = wLds[(wave << 7) | j];   // wave-uniform broadcast
        float g0 = ex2(fmaf(P.x, c0.x, fmaf(P.y, c0.y, fmaf(P.z, c0.z, c0.w)))) * P.w;
        float g1 = ex2(fmaf(P.x, c1.x, fmaf(P.y, c1.y, fmaf(P.z, c1.z, c1.w)))) * P.w;
        if (LAST) {
            grow[(size_t)j * KK] = g0;
            grow[(size_t)j * KK + 64] = g1;
        }
        ax0 = fmaf(g0, P.x, ax0); ay0 = fmaf(g0, P.y, ay0);
        az0 = fmaf(g0, P.z, az0); aw0 += g0;
        ax1 = fmaf(g1, P.x, ax1); ay1 = fmaf(g1, P.y, ay1);
        az1 = fmaf(g1, P.z, az1); aw1 += g1;
    }

    ((float4*)accW[wave])[lane]      = make_float4(ax0, ay0, az0, aw0);
    ((float4*)accW[wave])[lane + 64] = make_float4(ax1, ay1, az1, aw1);
    __syncthreads();
    float v0 = accW[0][tid]       + accW[1][tid]       + accW[2][tid]       + accW[3][tid];
    float v1 = accW[0][tid + 256] + accW[1][tid + 256] + accW[2][tid + 256] + accW[3][tid + 256];
    float* ag = accOut + b * (KK * 4);
    atomicAdd(ag + tid, v0);
    atomicAdd(ag + tid + 256, v1);
}

// ========= final: s_sum (inline) + node_xyz + pi from slice ITERS ==============
__global__ __launch_bounds__(256) void final_kernel(const float* __restrict__ sc,
                                                    const float* __restrict__ ws,
                                                    float* __restrict__ out) {
    int b = blockIdx.x, tid = threadIdx.x, wave = tid >> 6, lane = tid & 63;
    const float* S = sc + (size_t)b * NN;
    float sum = 0.f;
    for (int i = tid; i < NN; i += 256) sum += S[i];
    #pragma unroll
    for (int m = 1; m <= 32; m <<= 1) sum += __shfl_xor(sum, m, 64);
    __shared__ float red[4];
    if (lane == 0) red[wave] = sum;
    __syncthreads();
    if (tid < KK) {
        float ssum = red[0] + red[1] + red[2] + red[3] + EPSV;
        float4 a = ((const float4*)(ws + ITERS * SLICE_F))[b * KK + tid];
        float denom = a.w + EPSV;
        float* oxyz = out + XY_OFF + (size_t)(b * KK + tid) * 3;
        oxyz[0] = a.x / denom; oxyz[1] = a.y / denom; oxyz[2] = a.z / denom;
        out[PI_OFF + b * KK + tid] = a.w / ssum;
    }
}

// ====== nf_mfma2: nf[k][d] via 16x16x32 bf16 MFMA, atomic accumulate ======
__global__ __launch_bounds__(256) void nf_mfma2(const float* __restrict__ gamma,
                                                const float* __restrict__ feats,
                                                float* __restrict__ nf_acc) {
    __shared__ unsigned short gT[KK * 40];   // [k][pitch 40 bf16], 10240 B
    const int b = blockIdx.y, part = blockIdx.x;
    const int tid = threadIdx.x, wave = tid >> 6, lane = tid & 63;
    const int r = lane & 15, hi = lane >> 4;
    const int p = tid & 15, q0 = tid >> 4;

    f32x4 acc[2][4];
    #pragma unroll
    for (int kt = 0; kt < 2; kt++)
        #pragma unroll
        for (int dt = 0; dt < 4; dt++) acc[kt][dt] = (f32x4){0.f, 0.f, 0.f, 0.f};

    const float* gb = gamma + (size_t)b * NN * KK + (size_t)part * 256 * KK;
    const float* fb = feats + (size_t)b * DD * NN;
    const int n0 = part * 256;

    for (int ch = 0; ch < 8; ++ch) {
        const float* gr0 = gb + (size_t)(ch * 32 + 2 * p) * KK;
        const float* gr1 = gr0 + KK;
        unsigned* rowd = (unsigned*)gT;
        #pragma unroll
        for (int s = 0; s < 2; ++s) {
            int q = q0 + 16 * s;
            float4 x = *(const float4*)(gr0 + 4 * q);
            float4 y = *(const float4*)(gr1 + 4 * q);
            rowd[(4 * q + 0) * 20 + p] = pk2(x.x, y.x);
            rowd[(4 * q + 1) * 20 + p] = pk2(x.y, y.y);
            rowd[(4 * q + 2) * 20 + p] = pk2(x.z, y.z);
            rowd[(4 * q + 3) * 20 + p] = pk2(x.w, y.w);
        }
        __syncthreads();

        const unsigned short* a0p = gT + (wave * 32 + r) * 40 + hi * 8;
        short8 a0 = *(const short8*)a0p;
        short8 a1 = *(const short8*)(a0p + 16 * 40);
        const int nn = n0 + ch * 32 + hi * 8;
        #pragma unroll
        for (int dt = 0; dt < 4; ++dt) {
            const float* fr = fb + (size_t)(dt * 16 + r) * NN + nn;
            float4 x = *(const float4*)fr;
            float4 y = *(const float4*)(fr + 4);
            union { unsigned u[4]; short8 s; } bu;
            bu.u[0] = pk2(x.x, x.y); bu.u[1] = pk2(x.z, x.w);
            bu.u[2] = pk2(y.x, y.y); bu.u[3] = pk2(y.z, y.w);
            acc[0][dt] = __builtin_amdgcn_mfma_f32_16x16x32_bf16(a0, bu.s, acc[0][dt], 0, 0, 0);
            acc[1][dt] = __builtin_amdgcn_mfma_f32_16x16x32_bf16(a1, bu.s, acc[1][dt], 0, 0, 0);
        }
        __syncthreads();
    }

    float* nf = nf_acc + (size_t)b * KK * DD + (size_t)(wave * 32) * DD;
    #pragma unroll
    for (int kt = 0; kt < 2; kt++)
        #pragma unroll
        for (int dt = 0; dt < 4; dt++)
            #pragma unroll
            for (int rr = 0; rr < 4; rr++)
                atomicAdd(&nf[(kt * 16 + hi * 4 + rr) * DD + dt * 16 + r],
                          acc[kt][dt][rr]);
}

// ====== nf_finalize: divide accumulated nf by denom, in place ======
__global__ __launch_bounds__(256) void nf_finalize(const float* __restrict__ ws,
                                                   float* __restrict__ out) {
    int idx = blockIdx.x * 256 + threadIdx.x;   // [0, B*K*D)
    int bk = idx / DD;
    float denom = ws[ITERS * SLICE_F + bk * 4 + 3] + EPSV;
    out[NF_OUT + idx] = out[NF_OUT + idx] / denom;
}

extern "C" void kernel_launch(void* const* d_in, const int* in_sizes, int n_in,
                              void* d_out, int out_size, void* d_ws, size_t ws_size,
                              hipStream_t stream) {
    const float* xyz = (const float*)d_in[0];
    const float* feats = (const float*)d_in[1];
    const float* sc = (const float*)d_in[2];
    float* out = (float*)d_out;
    float* ws = (float*)d_ws;

    hipMemsetAsync(ws, 0, (size_t)HDR_F * sizeof(float), stream);
    hipMemsetAsync(out + NF_OUT, 0, (size_t)BB * KK * DD * sizeof(float), stream);

    assign_kernel<true, false><<<dim3(64, BB), 256, 0, stream>>>(
        xyz, sc, nullptr, ws + SLICE_F, out);
    for (int it = 1; it < ITERS - 1; it++) {
        assign_kernel<false, false><<<dim3(64, BB), 256, 0, stream>>>(
            xyz, sc, (const float4*)(ws + it * SLICE_F),
            ws + (it + 1) * SLICE_F, out);
    }
    assign_kernel<false, true><<<dim3(64, BB), 256, 0, stream>>>(
        xyz, sc, (const float4*)(ws + (ITERS - 1) * SLICE_F),
        ws + ITERS * SLICE_F, out);

    final_kernel<<<BB, 256, 0, stream>>>(sc, ws, out);
    nf_mfma2<<<dim3(JPARTS, BB), 256, 0, stream>>>(out, feats, out + NF_OUT);
    nf_finalize<<<256, 256, 0, stream>>>(ws, out);
}